// Round 8
// baseline (331.704 us; speedup 1.0000x reference)
//
#include <hip/hip_runtime.h>

#define DEVFN __device__ __forceinline__

typedef float  f32x4  __attribute__((ext_vector_type(4)));
typedef short  bf16x8 __attribute__((ext_vector_type(8)));

// Problem constants
constexpr int ENC = 168;
constexpr int DEC = 24;
constexpr int BT  = 16;            // batch tile (MFMA N)
constexpr int NBLK = 4096 / BT;    // 256 blocks -> 1 per CU

constexpr float LOG2E  = 1.4426950408889634f;
constexpr float LOG2E2 = 2.8853900817779268f;

// Workspace layout: VERIFIED round-0 gate-major tile layout, UNCHANGED.
// Tile tt = g*4 + wb holds gate g, units wb*16..wb*16+15 (n = tt*16 + row).
// K-maps: L0: k<20 x (c0), k==20 dup of col0 (lo-plane), k in[32,96) h0 (c1,c2)
//         L1: k<64 h0 (c1,c2), k in[64,128) h1 (c3,c4)
//         DEC: k<20 xin (c0), k==20 dup col0, k in[32,96) h1 (c3,c4)
constexpr int W0F = 0;             // 3*16*512 = 24576 ushorts
constexpr int W1F = 24576;         // 4*16*512 = 32768
constexpr int WDF = 57344;         // 3*16*512 = 24576
constexpr int F_B0   = 40960;
constexpr int F_B1   = 41216;
constexpr int F_BD   = 41472;
constexpr int F_WOUT = 41728;
constexpr int F_BOUT = 41792;
constexpr int F_EMB  = 41793;      // [574] hour120 wd24 mo52 woy378
constexpr int NEMB = 574;

DEVFN ushort f2bf(float v) {       // fp32 -> bf16 bits, RNE (scalar path)
    unsigned b = __float_as_uint(v);
    return (ushort)((b + 0x7FFFu + ((b >> 16) & 1u)) >> 16);
}
DEVFN float bf2f(ushort u) { return __uint_as_float(((unsigned)u) << 16); }
DEVFN unsigned cvt_pk_bf16(float a, float b) {  // hw packed RNE (lo=a, hi=b)
    unsigned r;
    asm("v_cvt_pk_bf16_f32 %0, %1, %2" : "=v"(r) : "v"(a), "v"(b));
    return r;
}
DEVFN float exp2n(float x) {       // 2^(-x), neg as free input modifier
    float r;
    asm("v_exp_f32 %0, -%1" : "=v"(r) : "v"(x));
    return r;
}
// pin a value into registers: asm consumes+redefines it -> no remat of the load
DEVFN void pinv(bf16x8& v) { asm volatile("" : "+v"(v)); }
DEVFN void pinf(f32x4& v)  { asm volatile("" : "+v"(v)); }

// LSTM cell on pre-scaled gates (i,f,o x log2e; g x 2log2e), fused-rcp pairs.
DEVFN float lstm_cell(float gi, float gf, float gg, float go, float& c) {
    float a  = exp2n(fmaxf(gi, -21.f));            // e^-i
    float b  = exp2n(fmaxf(gg, -43.f));            // e^-2g
    float f  = exp2n(gf);                          // e^-f
    float sf = __builtin_amdgcn_rcpf(1.f + f);
    float it = (1.f - b) * __builtin_amdgcn_rcpf(fmaf(a, b, a + b + 1.f));
    c = fmaf(sf, c, it);
    float d  = exp2n(fmaxf(c, -15.f) * LOG2E2);    // e^-2c
    float o  = exp2n(fmaxf(go, -21.f));            // e^-o
    return (1.f - d) * __builtin_amdgcn_rcpf(fmaf(o, d, o + d + 1.f));
}

// ---------------- prep: weights -> bf16 MFMA fragments (pre-scaled) --------
// EXACT round-0 prep (verified family, absmax 2.441406e-04).
__global__ void prep_kernel(
    const float* __restrict__ w0ih, const float* __restrict__ w0hh,
    const float* __restrict__ b0ih, const float* __restrict__ b0hh,
    const float* __restrict__ w1ih, const float* __restrict__ w1hh,
    const float* __restrict__ b1ih, const float* __restrict__ b1hh,
    const float* __restrict__ wdih, const float* __restrict__ wdhh,
    const float* __restrict__ bdih, const float* __restrict__ bdhh,
    const float* __restrict__ wout, const float* __restrict__ boutp,
    const float* __restrict__ eh,   const float* __restrict__ ewd,
    const float* __restrict__ emo,  const float* __restrict__ ewoy,
    void* __restrict__ ws)
{
    ushort* wsu = (ushort*)ws;
    float*  wsf = (float*)ws;
    const int total = 81920 + 1407;
    for (int idx = blockIdx.x * blockDim.x + threadIdx.x; idx < total;
         idx += gridDim.x * blockDim.x) {
        if (idx < 81920) {
            int layer, q;
            if (idx < W1F)      { layer = 0; q = idx; }
            else if (idx < WDF) { layer = 1; q = idx - W1F; }
            else                { layer = 2; q = idx - WDF; }
            int c  = q >> 13;
            int tt = (q >> 9) & 15;
            int l  = (q >> 3) & 63;
            int j  = q & 7;
            int k  = c * 32 + (l >> 4) * 8 + j;
            int n  = tt * 16 + (l & 15);
            float v = 0.f;
            if (layer == 0) {
                if (k < 20) v = w0ih[n * 20 + k];
                else if (k == 20) v = w0ih[n * 20];            // lo-plane dup of col0
                else if (k >= 32 && k < 96) v = w0hh[n * 64 + (k - 32)];
            } else if (layer == 1) {
                if (k < 64) v = w1ih[n * 64 + k];
                else        v = w1hh[n * 64 + (k - 64)];
            } else {
                if (k < 20) v = wdih[n * 20 + k];
                else if (k == 20) v = wdih[n * 20];            // lo-plane dup of col0
                else if (k >= 32 && k < 96) v = wdhh[n * 64 + (k - 32)];
            }
            v *= ((n >> 6) == 2) ? LOG2E2 : LOG2E;   // pre-scale for exp2
            wsu[idx] = f2bf(v);
        } else {
            int f = idx - 81920;
            float v;
            if (f < 768) {
                float sc = (((f & 255) >> 6) == 2) ? LOG2E2 : LOG2E;
                if (f < 256)      v = (b0ih[f] + b0hh[f]) * sc;
                else if (f < 512) v = (b1ih[f - 256] + b1hh[f - 256]) * sc;
                else              v = (bdih[f - 512] + bdhh[f - 512]) * sc;
            }
            else if (f < 832) v = wout[f - 768];
            else if (f == 832) v = boutp[0];
            else {
                int e = f - 833;
                if (e < 120)      v = eh[e];
                else if (e < 144) v = ewd[e - 120];
                else if (e < 196) v = emo[e - 144];
                else              v = ewoy[e - 196];
            }
            wsf[40960 + f] = v;
        }
    }
}

DEVFN int offX(int k, int m) {     // chunk0 fragment offset, k in [0,32)
    return (m + 16 * (k >> 3)) * 8 + (k & 7);
}
// hi/lo pair for the k=0 feature (label/prev): hi at k=0, lo at k=20
DEVFN void store_prev(ushort* A, int m, float v) {
    ushort hi = f2bf(v);
    A[offX(0, m)]  = hi;
    A[offX(20, m)] = f2bf(v - bf2f(hi));
}

// ---------------- main persistent MFMA kernel: 1024 thr, 16 waves ----------
// GATE-PAIR SPLIT of the verified round-0 schedule. Wave (wb=w&3, gh=(w>>2)&1,
// layer = w<8 ? L0 : L1) computes round-0 tiles {(2gh)*4+wb, (2gh+1)*4+wb}
// with the IDENTICAL MFMA chains/fragments/bias-C-init -> gate values are
// bit-identical to round 0. Each lane owns 2 cells (units u0+2gh, u0+2gh+1);
// the 2 missing gates come from partner wave w^4 via fp32 LDS planes (exact).
// cvt_pk pairings and all store positions match round 0 -> absmax must be
// EXACTLY 2.441406e-04. Per-wave serial work halves; 4 waves/SIMD hide the
// chain latency that stalls the 2-wave round-0 schedule ~48% of cycles.
// LDS padded >81920 B (r6-proven): 1 WG/CU target -> 128-VGPR budget, no
// spill (r2/r5 failure mode). No waves_per_eu attr.
__global__ __launch_bounds__(1024)
void lstm_mfma(
    const int* __restrict__ input_time, const float* __restrict__ label_p,
    const int* __restrict__ decoder_time, const void* __restrict__ ws,
    float* __restrict__ out)
{
    const ushort* wsu = (const ushort*)ws;
    const float*  wsf = (const float*)ws;

    // double-buffered activations: c0=x/xin, c1c2=h0, c3c4=h1 (bf16 frags)
    __shared__ __align__(16) ushort Abuf[2][5 * 512];
    // gate-exchange planes: [elem01 of A-gate, elem01 of B-gate][wave][lane]
    // bank = lane%32 -> 2-way (free) on both write and read
    __shared__ float XP[4][16][64];
    __shared__ float s_emb[NEMB];
    __shared__ float s_wout[64];
    __shared__ float sh1[16 * 68];     // [m][u] padded
    __shared__ float s_bout;
    __shared__ ushort s_pad[24576];    // 49152 B pad -> total LDS > 81920 B

    const int tid = threadIdx.x;
    const int w   = tid >> 6;          // wave 0..15
    const int l   = tid & 63;
    const int q   = l >> 4;
    const int m   = l & 15;
    const int wb  = w & 3;             // unit block
    const int gh  = (w >> 2) & 1;      // gate half: 0 -> gates 0,1; 1 -> 2,3
    const bool isL0 = (w < 8);
    const int pw  = w ^ 4;             // partner wave (other gate half)
    const int b0g = blockIdx.x * BT;
    const int u0  = wb * 16 + q * 4;   // tile's 4 units at this lane
    const int rr  = gh * 2;            // my 2 cell elems within the tile
    const int pr  = 2 - rr;            // elems I ship to partner

    // keep the LDS pad alive (opaque never-true condition; r6-proven)
    if (label_p == nullptr) ((volatile ushort*)s_pad)[tid & 1023] = 0;

    // h store offset for my pair (same element positions as round-0 b64)
    const int hoff = (1 + (u0 >> 5)) * 512 +
                     (m + 16 * ((u0 & 31) >> 3)) * 8 + (u0 & 7) +
                     (isL0 ? 0 : 1024) + rr;

    // ---- init ----
    for (int i = tid; i < 2 * 5 * 512; i += 1024) ((ushort*)Abuf)[i] = 0;
    for (int i = tid; i < NEMB; i += 1024) s_emb[i] = wsf[F_EMB + i];
    if (tid < 64) s_wout[tid] = wsf[F_WOUT + tid];
    if (tid == 0) s_bout = wsf[F_BOUT];

    // ---- weight fragments: 2 gate-tiles x NC chunks, pinned in VGPRs ----
    bf16x8 wA[4][2];                   // [chunk][s]; s -> gate 2gh+s
    if (isL0) {
#pragma unroll
        for (int c = 0; c < 3; c++)
#pragma unroll
            for (int s = 0; s < 2; s++)
                wA[c][s] = *(const bf16x8*)(wsu + W0F +
                    (c * 16 + (2 * gh + s) * 4 + wb) * 512 + l * 8);
#pragma unroll
        for (int c = 0; c < 3; c++) { pinv(wA[c][0]); pinv(wA[c][1]); }
    } else {
#pragma unroll
        for (int c = 0; c < 4; c++)
#pragma unroll
            for (int s = 0; s < 2; s++)
                wA[c][s] = *(const bf16x8*)(wsu + W1F +
                    (c * 16 + (2 * gh + s) * 4 + wb) * 512 + l * 8);
#pragma unroll
        for (int c = 0; c < 4; c++) { pinv(wA[c][0]); pinv(wA[c][1]); }
    }

    f32x4 biasv[2];
#pragma unroll
    for (int s = 0; s < 2; s++) {
        biasv[s] = *(const f32x4*)(wsf + (isL0 ? F_B0 : F_B1) +
                                   (2 * gh + s) * 64 + u0);
        pinf(biasv[s]);
    }

    float cst[2] = {0.f, 0.f};         // cell state for units u0+rr, u0+rr+1

    // x-build roles (round-0 values exactly): primary kk1 for tid<256,
    // secondary kk2 = kk1+16 for tid<64. batch = tid&15 = m.
    const int kk1 = tid >> 4;
    const int kk2 = kk1 + 16;
    const bool xb1 = (tid < 256);
    const bool xb2 = (tid < 64);
    int sel1 = 0, estr1 = 0, ebase1 = 0;
    if (kk1 >= 1 && kk1 < 16) {
        int f = kk1 - 1;
        if (f < 5)       { sel1 = 0; estr1 = 5; ebase1 = 0   + f; }
        else if (f < 8)  { sel1 = 1; estr1 = 3; ebase1 = 120 + (f - 5); }
        else if (f < 12) { sel1 = 2; estr1 = 4; ebase1 = 144 + (f - 8); }
        else             { sel1 = 3; estr1 = 7; ebase1 = 196 + (f - 12); }
    }
    const int ebase2 = 196 + (kk2 - 13);   // woy table, stride 7

    __syncthreads();
    if (xb1) {    // x(0) into Abuf[0]
        if (kk1 == 0) {
            store_prev(Abuf[0], m, label_p[(b0g + m) * ENC]);
        } else {
            int idx = input_time[((b0g + m) * ENC) * 4 + sel1];
            Abuf[0][offX(kk1, m)] = f2bf(s_emb[ebase1 + idx * estr1]);
        }
    }
    if (xb2) {
        int idx2 = input_time[((b0g + m) * ENC) * 4 + 3];
        Abuf[0][offX(kk2, m)] = f2bf(s_emb[ebase2 + idx2 * 7]);
    }
    __syncthreads();

    // ============ encoder pipeline: iter i = layer0(i) + layer1(i-1) ========
    for (int i = 0; i <= ENC; ++i) {
        const ushort* Ar = Abuf[i & 1];
        ushort* Aw = Abuf[(i + 1) & 1];
        const bool active = isL0 ? (i < ENC) : (i >= 1);

        // prefetch globals for next x (consumed in phase 2)
        float pre_f = 0.f; int pre_i1 = 0, pre_i2 = 0;
        const bool encX  = (i + 1 < ENC) && xb1;
        const bool decX0 = (i == ENC) && xb1;
        if (encX) {
            if (kk1 == 0) pre_f  = label_p[(b0g + m) * ENC + (i + 1)];
            else          pre_i1 = input_time[((b0g + m) * ENC + (i + 1)) * 4 + sel1];
            if (xb2)      pre_i2 = input_time[((b0g + m) * ENC + (i + 1)) * 4 + 3];
        } else if (decX0) {
            if (kk1 == 0) pre_f  = label_p[(b0g + m) * ENC + (ENC - 1)];
            else          pre_i1 = decoder_time[((b0g + m) * DEC) * 4 + sel1];
            if (xb2)      pre_i2 = decoder_time[((b0g + m) * DEC) * 4 + 3];
        }

        // ---- phase 1: MFMA gate-pair tiles + ship partner halves ----
        f32x4 acc[2];
        if (active) {
            if (isL0) {
                bf16x8 ah[3];
#pragma unroll
                for (int c = 0; c < 3; c++)
                    ah[c] = *(const bf16x8*)(Ar + c * 512 + l * 8);
#pragma unroll
                for (int s = 0; s < 2; s++)
                    acc[s] = __builtin_amdgcn_mfma_f32_16x16x32_bf16(
                        wA[0][s], ah[0], biasv[s], 0, 0, 0);
#pragma unroll
                for (int c = 1; c < 3; c++)
#pragma unroll
                    for (int s = 0; s < 2; s++)
                        acc[s] = __builtin_amdgcn_mfma_f32_16x16x32_bf16(
                            wA[c][s], ah[c], acc[s], 0, 0, 0);
            } else {
                bf16x8 ah[4];
#pragma unroll
                for (int c = 0; c < 4; c++)
                    ah[c] = *(const bf16x8*)(Ar + (1 + c) * 512 + l * 8);
#pragma unroll
                for (int s = 0; s < 2; s++)
                    acc[s] = __builtin_amdgcn_mfma_f32_16x16x32_bf16(
                        wA[0][s], ah[0], biasv[s], 0, 0, 0);
#pragma unroll
                for (int c = 1; c < 4; c++)
#pragma unroll
                    for (int s = 0; s < 2; s++)
                        acc[s] = __builtin_amdgcn_mfma_f32_16x16x32_bf16(
                            wA[c][s], ah[c], acc[s], 0, 0, 0);
            }
            XP[0][w][l] = acc[0][pr];
            XP[1][w][l] = acc[0][pr + 1];
            XP[2][w][l] = acc[1][pr];
            XP[3][w][l] = acc[1][pr + 1];
        }
        __syncthreads();   // partner gate halves published

        // ---- phase 2: 2 lane-local cells + h store + x-build writes ----
        if (active) {
            float pA0 = XP[0][pw][l], pA1 = XP[1][pw][l];
            float pB0 = XP[2][pw][l], pB1 = XP[3][pw][l];
            float hv0, hv1;
            if (gh == 0) {   // own i,f; partner g,o
                hv0 = lstm_cell(acc[0][0], acc[1][0], pA0, pB0, cst[0]);
                hv1 = lstm_cell(acc[0][1], acc[1][1], pA1, pB1, cst[1]);
            } else {         // partner i,f; own g,o
                hv0 = lstm_cell(pA0, pB0, acc[0][2], acc[1][2], cst[0]);
                hv1 = lstm_cell(pA1, pB1, acc[0][3], acc[1][3], cst[1]);
            }
            unsigned pk = cvt_pk_bf16(hv0, hv1);   // round-0 pairing exactly
            asm volatile("" : "+v"(pk));
            *(unsigned*)(Aw + hoff) = pk;
        }
        if (encX || decX0) {
            if (kk1 == 0) store_prev(Aw, m, pre_f);
            else          Aw[offX(kk1, m)] = f2bf(s_emb[ebase1 + pre_i1 * estr1]);
            if (xb2)      Aw[offX(kk2, m)] = f2bf(s_emb[ebase2 + pre_i2 * 7]);
        }
        __syncthreads();   // Aw complete
    }

    // ============ decoder: waves 8-15 compute (cst carries h1 state) =======
    if (!isL0) {
#pragma unroll
        for (int c = 0; c < 3; c++)
#pragma unroll
            for (int s = 0; s < 2; s++)
                wA[c][s] = *(const bf16x8*)(wsu + WDF +
                    (c * 16 + (2 * gh + s) * 4 + wb) * 512 + l * 8);
#pragma unroll
        for (int c = 0; c < 3; c++) { pinv(wA[c][0]); pinv(wA[c][1]); }
#pragma unroll
        for (int s = 0; s < 2; s++) {
            biasv[s] = *(const f32x4*)(wsf + F_BD + (2 * gh + s) * 64 + u0);
            pinf(biasv[s]);
        }
    }

    for (int t = 0; t < DEC; ++t) {
        const ushort* Ar = Abuf[(t + 1) & 1];
        ushort* Aw = Abuf[t & 1];

        int pre_i1 = 0, pre_i2 = 0;
        const bool dX = (t + 1 < DEC) && xb1;
        if (dX) {
            if (kk1 >= 1) pre_i1 = decoder_time[((b0g + m) * DEC + (t + 1)) * 4 + sel1];
            if (xb2)      pre_i2 = decoder_time[((b0g + m) * DEC + (t + 1)) * 4 + 3];
        }

        // ---- phase 1: DEC gate-pair MFMA + ship partner halves ----
        f32x4 acc[2];
        if (!isL0) {
            bf16x8 ah[3];
            ah[0] = *(const bf16x8*)(Ar + 0 * 512 + l * 8);   // xin (c0)
            ah[1] = *(const bf16x8*)(Ar + 3 * 512 + l * 8);   // h1 lo (c3)
            ah[2] = *(const bf16x8*)(Ar + 4 * 512 + l * 8);   // h1 hi (c4)
#pragma unroll
            for (int s = 0; s < 2; s++)
                acc[s] = __builtin_amdgcn_mfma_f32_16x16x32_bf16(
                    wA[0][s], ah[0], biasv[s], 0, 0, 0);
#pragma unroll
            for (int c = 1; c < 3; c++)
#pragma unroll
                for (int s = 0; s < 2; s++)
                    acc[s] = __builtin_amdgcn_mfma_f32_16x16x32_bf16(
                        wA[c][s], ah[c], acc[s], 0, 0, 0);
            XP[0][w][l] = acc[0][pr];
            XP[1][w][l] = acc[0][pr + 1];
            XP[2][w][l] = acc[1][pr];
            XP[3][w][l] = acc[1][pr + 1];
        }
        __syncthreads();

        // ---- phase 2: cells + h/sh1 stores + x-build writes ----
        if (!isL0) {
            float pA0 = XP[0][pw][l], pA1 = XP[1][pw][l];
            float pB0 = XP[2][pw][l], pB1 = XP[3][pw][l];
            float hv0, hv1;
            if (gh == 0) {
                hv0 = lstm_cell(acc[0][0], acc[1][0], pA0, pB0, cst[0]);
                hv1 = lstm_cell(acc[0][1], acc[1][1], pA1, pB1, cst[1]);
            } else {
                hv0 = lstm_cell(pA0, pB0, acc[0][2], acc[1][2], cst[0]);
                hv1 = lstm_cell(pA1, pB1, acc[0][3], acc[1][3], cst[1]);
            }
            unsigned pk = cvt_pk_bf16(hv0, hv1);
            asm volatile("" : "+v"(pk));
            *(unsigned*)(Aw + hoff) = pk;               // h1 recurrent -> c3c4
            sh1[m * 68 + u0 + rr]     = hv0;
            sh1[m * 68 + u0 + rr + 1] = hv1;
        }
        if (dX && kk1 >= 1) Aw[offX(kk1, m)] = f2bf(s_emb[ebase1 + pre_i1 * estr1]);
        if (dX && xb2)      Aw[offX(kk2, m)] = f2bf(s_emb[ebase2 + pre_i2 * 7]);
        __syncthreads();

        // ---- phase 3: projection (verified round-0 summation order) ----
        if (tid < 16) {
            float a = s_bout;
#pragma unroll 16
            for (int u = 0; u < 64; u++) a = fmaf(s_wout[u], sh1[tid * 68 + u], a);
            out[(b0g + tid) * DEC + t] = a;
            if (t + 1 < DEC) store_prev(Aw, tid, a);   // fp32-accurate prev
        }
        __syncthreads();
    }
}

extern "C" void kernel_launch(void* const* d_in, const int* in_sizes, int n_in,
                              void* d_out, int out_size, void* d_ws, size_t ws_size,
                              hipStream_t stream)
{
    typedef const float* fp;
    const int* input_time   = (const int*)d_in[1];
    fp         label_p      = (fp)d_in[2];
    const int* decoder_time = (const int*)d_in[3];

    prep_kernel<<<128, 256, 0, stream>>>(
        (fp)d_in[4],  (fp)d_in[5],  (fp)d_in[6],  (fp)d_in[7],
        (fp)d_in[8],  (fp)d_in[9],  (fp)d_in[10], (fp)d_in[11],
        (fp)d_in[12], (fp)d_in[13], (fp)d_in[14], (fp)d_in[15],
        (fp)d_in[16], (fp)d_in[17],
        (fp)d_in[18], (fp)d_in[19], (fp)d_in[20], (fp)d_in[21],
        d_ws);

    lstm_mfma<<<NBLK, 1024, 0, stream>>>(
        input_time, label_p, decoder_time, d_ws, (float*)d_out);
}